// Round 8
// baseline (203.983 us; speedup 1.0000x reference)
//
#include <hip/hip_runtime.h>
#include <hip/hip_bf16.h>

#define HID 128
#define INP 64
#define SPANN 8
#define NOUT 2
#define DAYS 20
#define ROWS 128            // 4 n-tiles of 32 rows; grid = 256 = 1 block/CU
#define NTH 512             // 8 waves

typedef __attribute__((ext_vector_type(8)))  short short8;
typedef __attribute__((ext_vector_type(16))) float f32x16;
typedef __attribute__((ext_vector_type(4)))  float f32x4;
typedef __attribute__((ext_vector_type(2)))  float f32x2;
typedef unsigned int u32;
typedef __attribute__((ext_vector_type(2)))  u32 u32x2;
typedef unsigned short u16;

#define MFMA32(a,b,c) __builtin_amdgcn_mfma_f32_32x32x16_bf16(a,b,c,0,0,0)
#define RCPF(x)  __builtin_amdgcn_rcpf(x)
#define EXP2F(x) __builtin_amdgcn_exp2f(x)
#define LOG2E   1.4426950408889634f
#define NLOG2E  (-1.4426950408889634f)
#define LOG2E2  2.8853900817779268f

__device__ __forceinline__ u32 pack2(float a, float b){
    __hip_bfloat162 h = __float22bfloat162_rn(float2{a, b});
    u32 r; __builtin_memcpy(&r, &h, 4); return r;
}
__device__ __forceinline__ u16 bf16u(float v){ return (u16)(pack2(v, v) & 0xFFFFu); }
__device__ __forceinline__ float asF(u32 u){ union{u32 u; float f;} v; v.u = u; return v.f; }
// pre-scaled activations: arg already multiplied by -log2e (sig) / 2log2e (tanh)
__device__ __forceinline__ float sig2(float a){ return RCPF(1.0f + EXP2F(a)); }
__device__ __forceinline__ float tanh2(float a){ return fmaf(-2.0f, RCPF(1.0f + EXP2F(a)), 1.0f); }

union frag_u { short8 s; u32 w[4]; };
// load 8 consecutive f32, scale, convert to one 32x32x16 bf16 A/B fragment (4 VGPRs)
__device__ __forceinline__ short8 ldfrag(const float* p, float sc){
    const f32x4 a = *(const f32x4*)p;
    const f32x4 b = *(const f32x4*)(p+4);
    frag_u f;
    f.w[0] = pack2(sc*a[0],sc*a[1]); f.w[1] = pack2(sc*a[2],sc*a[3]);
    f.w[2] = pack2(sc*b[0],sc*b[1]); f.w[3] = pack2(sc*b[2],sc*b[3]);
    return f.s;
}

// ---- 32x32x16 fragment conventions (slot-space; k-bijection shared by A and B
// so any HW k-permutation cancels; C/D map is m74/m101-verified) ----
//  A: lane l holds A[m = (l&31) + mslice*32][k = ks*16 + (l>>5)*8 + j]
//  B: lane l holds B[k = ks*16 + (l>>5)*8 + j][n = l&31]
//  D: elem q -> row m_loc = (q&3) + 8*(q>>2) + 4*(l>>5), col n = l&31
// hL layout: [buf2][nt4][ks9][lane64][8 bf16]; ks=8 is a STATIC ones-column
// (k=128 == 1.0) so biases enter via one extra MFMA per gate (no bias VGPRs).
// xL: [nt4][ks4][lane64][8]. Gate weights pre-scaled: R/Z by -log2e, N by 2log2e.

__global__ __launch_bounds__(NTH, 2) void gru32(
    const float* __restrict__ hx, const float* __restrict__ w_ih,
    const float* __restrict__ w_hh, const float* __restrict__ b_ih,
    const float* __restrict__ b_hh, const float* __restrict__ fc_in_w,
    const float* __restrict__ fc_in_b, const float* __restrict__ fc_out_w,
    const float* __restrict__ fc_out_b, const float* __restrict__ span_w,
    const float* __restrict__ span_b, float* __restrict__ out, int bs)
{
    __shared__ __attribute__((aligned(16))) u16 hL[36864];   // 72 KiB: 2 bufs
    __shared__ __attribute__((aligned(16))) u16 xL[8192];    // 16 KiB
    __shared__ __attribute__((aligned(16))) u16 finL[9216];  // 18 KiB: fc_in A-frags (ks0-7) + bias col (ks8)
    __shared__ u16 biasBL[512];                              // scaled gate biases bf16 [4 gates][128]
    __shared__ float wdL[128];                               // scaled fc_out diff weights
    __shared__ __attribute__((aligned(16))) float diffP[128][4];

    const int tid = threadIdx.x;
    const int wid = tid >> 6;
    const int l   = tid & 63;
    const int n31 = l & 31;
    const int kg  = l >> 5;
    const int row0 = blockIdx.x * ROWS;
    const int ms  = wid & 3;        // gate m-slice (32 cols x 3 gates)
    const int nt0 = wid >> 2;       // gate n-tiles: nt0 and nt0+2
    const int msF = wid & 1;        // fc_in m-slice
    const int ntF = wid >> 1;       // fc_in n-tile

    // ---- resident gate weight fragments (144 VGPR) ----
    short8 whhR[8], whhZ[8], whhN[8];
    short8 wihR[4], wihZ[4], wihN[4];
    {
        const int mr = ms*32 + n31;
        #pragma unroll
        for (int ks = 0; ks < 8; ++ks){
            whhR[ks] = ldfrag(w_hh + (size_t)(      mr)*HID + ks*16 + kg*8, NLOG2E);
            whhZ[ks] = ldfrag(w_hh + (size_t)(128 + mr)*HID + ks*16 + kg*8, NLOG2E);
            whhN[ks] = ldfrag(w_hh + (size_t)(256 + mr)*HID + ks*16 + kg*8, LOG2E2);
        }
        #pragma unroll
        for (int ks = 0; ks < 4; ++ks){
            wihR[ks] = ldfrag(w_ih + (size_t)(      mr)*INP + ks*16 + kg*8, NLOG2E);
            wihZ[ks] = ldfrag(w_ih + (size_t)(128 + mr)*INP + ks*16 + kg*8, NLOG2E);
            wihN[ks] = ldfrag(w_ih + (size_t)(256 + mr)*INP + ks*16 + kg*8, LOG2E2);
        }
    }
    // ones B-fragment (k=128 -> 1.0): constant, 4 VGPR
    frag_u ob; ob.w[0] = (l < 32) ? 0x00003F80u : 0u; ob.w[1]=0; ob.w[2]=0; ob.w[3]=0;
    const short8 onesB = ob.s;
    const float bd = NLOG2E*(fc_out_b[0] - fc_out_b[1]);

    // ---- stage hx -> hL buf0 (coalesced f32x4 reads) ----
    #pragma unroll
    for (int i = 0; i < 8; ++i){
        const int idx = tid + NTH*i;               // 4096 f32x4 slots
        const int row = idx >> 5, c4 = idx & 31;
        const f32x4 v = ((const f32x4*)hx)[(size_t)(row0 + row)*32 + c4];
        const int nt = row >> 5, nr = row & 31;
        const int ks = c4 >> 2, kg2 = (c4 >> 1) & 1, jh = c4 & 1;
        u32* p = (u32*)&hL[nt*4608 + ks*512 + (nr + 32*kg2)*8 + jh*4];
        u32x2 wv; wv[0] = pack2(v[0], v[1]); wv[1] = pack2(v[2], v[3]);
        *(u32x2*)p = wv;
    }
    // ones rows (ks=8) in BOTH buffers
    for (int idx = tid; idx < 512; idx += NTH){
        const int buf = idx >> 8, nt = (idx >> 6) & 3, l2 = idx & 63;
        u32* p = (u32*)&hL[buf*18432 + nt*4608 + 8*512 + l2*8];
        u32x2 a; a[0] = (l2 < 32) ? 0x00003F80u : 0u; a[1] = 0;
        u32x2 z; z[0] = 0; z[1] = 0;
        *(u32x2*)p = a; *((u32x2*)p + 1) = z;
    }
    // zero xL
    for (int idx = tid; idx < 2048; idx += NTH){
        u32x2 z; z[0] = 0; z[1] = 0; ((u32x2*)xL)[idx] = z;
    }
    // fc_in A-frags + bias column
    for (int s = tid; s < 1152; s += NTH){
        const int msf = (s >= 576) ? 1 : 0, r = s - msf*576;
        const int ks = r >> 6, l2 = r & 63;
        short8 f;
        if (ks < 8){
            f = ldfrag(fc_in_w + (size_t)(msf*32 + (l2&31))*HID + ks*16 + (l2>>5)*8, 1.0f);
        } else {
            frag_u u; u.w[0] = (l2 < 32) ? (u32)bf16u(fc_in_b[msf*32 + (l2&31)]) : 0u;
            u.w[1]=0; u.w[2]=0; u.w[3]=0; f = u.s;
        }
        *((short8*)finL + msf*576 + ks*64 + l2) = f;
    }
    // scaled gate biases (bf16) + fc_out diff weights
    for (int idx = tid; idx < 512; idx += NTH){
        const int g = idx >> 7, c = idx & 127;
        float v;
        if      (g == 0) v = NLOG2E*(b_ih[c]       + b_hh[c]);
        else if (g == 1) v = NLOG2E*(b_ih[128 + c] + b_hh[128 + c]);
        else if (g == 2) v = LOG2E2* b_hh[256 + c];
        else             v = LOG2E2* b_ih[256 + c];
        biasBL[idx] = bf16u(v);
    }
    if (tid < 128) wdL[tid] = NLOG2E*(fc_out_w[tid] - fc_out_w[128 + tid]);
    __syncthreads();

    // ---- span head: waves 0-3, n-tile = wid (reads hL buf0; no barrier needed:
    // buf0 is not overwritten until day-1 phase A, which is 2 barriers away) ----
    if (wid < 4){
        const short8 zz = {0,0,0,0,0,0,0,0};
        short8 spw[8];
        #pragma unroll
        for (int ks = 0; ks < 8; ++ks)
            spw[ks] = (n31 < SPANN) ? ldfrag(span_w + (size_t)n31*HID + ks*16 + kg*8, 1.0f) : zz;
        f32x16 acc = {0,0,0,0,0,0,0,0,0,0,0,0,0,0,0,0};
        const short8* hb = (const short8*)&hL[wid*4608];
        #pragma unroll
        for (int ks = 0; ks < 8; ++ks) acc = MFMA32(spw[ks], hb[ks*64 + l], acc);
        const f32x4 sb = *(const f32x4*)(span_b + kg*4);   // spans kg*4+q, q=0..3
        const float s0 = acc[0]+sb[0], s1 = acc[1]+sb[1], s2 = acc[2]+sb[2], s3 = acc[3]+sb[3];
        float m = fmaxf(fmaxf(s0, s1), fmaxf(s2, s3));
        m = fmaxf(m, __shfl_xor(m, 32));
        const float e0 = EXP2F(LOG2E*(s0-m)), e1 = EXP2F(LOG2E*(s1-m));
        const float e2 = EXP2F(LOG2E*(s2-m)), e3 = EXP2F(LOG2E*(s3-m));
        float sum = (e0+e1) + (e2+e3);
        sum += __shfl_xor(sum, 32);
        const float inv = RCPF(sum);
        f32x4 o = {e0*inv, e1*inv, e2*inv, e3*inv};
        *(f32x4*)(out + (size_t)(row0 + wid*32 + n31)*SPANN + kg*4) = o;
    }

    float* __restrict__ outp = out + (size_t)bs * SPANN;

    #pragma unroll 1
    for (int d = 0; d < DAYS; ++d){
        const u16* hRd = hL + (d & 1)*18432;
        u16*       hWr = hL + ((d & 1) ^ 1)*18432;

        // ============ Phase A: gates, n-tiles nt0 and nt0+2 ============
        #pragma unroll
        for (int t = 0; t < 2; ++t){
            const int nt = nt0 + 2*t;
            const short8* hb = (const short8*)(hRd + nt*4608);
            const short8* xb = (const short8*)(xL  + nt*2048);

            // bias A-frags rebuilt from LDS (cheap; keeps them out of VGPRs)
            frag_u bR_, bZ_, bNh_, bNi_;
            bR_.w[0]  = (l<32) ? (u32)biasBL[      ms*32 + n31] : 0u; bR_.w[1]=0;  bR_.w[2]=0;  bR_.w[3]=0;
            bZ_.w[0]  = (l<32) ? (u32)biasBL[128 + ms*32 + n31] : 0u; bZ_.w[1]=0;  bZ_.w[2]=0;  bZ_.w[3]=0;
            bNh_.w[0] = (l<32) ? (u32)biasBL[256 + ms*32 + n31] : 0u; bNh_.w[1]=0; bNh_.w[2]=0; bNh_.w[3]=0;
            bNi_.w[0] = (l<32) ? (u32)biasBL[384 + ms*32 + n31] : 0u; bNi_.w[1]=0; bNi_.w[2]=0; bNi_.w[3]=0;

            f32x16 aR  = {0,0,0,0,0,0,0,0,0,0,0,0,0,0,0,0};
            f32x16 aZ  = {0,0,0,0,0,0,0,0,0,0,0,0,0,0,0,0};
            f32x16 aNh = {0,0,0,0,0,0,0,0,0,0,0,0,0,0,0,0};
            f32x16 aNi = {0,0,0,0,0,0,0,0,0,0,0,0,0,0,0,0};
            aR  = MFMA32(bR_.s,  onesB, aR);
            aZ  = MFMA32(bZ_.s,  onesB, aZ);
            aNh = MFMA32(bNh_.s, onesB, aNh);
            aNi = MFMA32(bNi_.s, onesB, aNi);
            #pragma unroll
            for (int ks = 0; ks < 8; ++ks){
                const short8 hf = hb[ks*64 + l];
                aR  = MFMA32(whhR[ks], hf, aR);
                aZ  = MFMA32(whhZ[ks], hf, aZ);
                aNh = MFMA32(whhN[ks], hf, aNh);
            }
            #pragma unroll
            for (int ks = 0; ks < 4; ++ks){
                const short8 xf = xb[ks*64 + l];
                aR  = MFMA32(wihR[ks], xf, aR);
                aZ  = MFMA32(wihZ[ks], xf, aZ);
                aNi = MFMA32(wihN[ks], xf, aNi);
            }

            // h_old (bf16 trajectory, proven in R6): 4 b64 at own scatter addrs
            const u32* hoB = (const u32*)hRd + nt*2304 + ms*512 + n31*4 + 2*kg;
            const u32x2 q0 = *(const u32x2*)(hoB      );
            const u32x2 q1 = *(const u32x2*)(hoB + 128);
            const u32x2 q2 = *(const u32x2*)(hoB + 256);
            const u32x2 q3 = *(const u32x2*)(hoB + 384);
            const u32 how[8] = {q0[0],q0[1],q1[0],q1[1],q2[0],q2[1],q3[0],q3[1]};

            float hn[16];
            #pragma unroll
            for (int q = 0; q < 16; ++q){
                const float hold = (q & 1) ? asF(how[q>>1] & 0xFFFF0000u)
                                           : asF(how[q>>1] << 16);
                const float rg = sig2(aR[q]);
                const float zg = sig2(aZ[q]);
                const float nn = tanh2(fmaf(rg, aNh[q], aNi[q]));
                hn[q] = fmaf(zg, hold - nn, nn);
            }
            u32* hw = (u32*)hWr + nt*2304 + ms*512 + n31*4 + 2*kg;
            { u32x2 wv; wv[0]=pack2(hn[0],hn[1]);   wv[1]=pack2(hn[2],hn[3]);   *(u32x2*)(hw      ) = wv; }
            { u32x2 wv; wv[0]=pack2(hn[4],hn[5]);   wv[1]=pack2(hn[6],hn[7]);   *(u32x2*)(hw + 128) = wv; }
            { u32x2 wv; wv[0]=pack2(hn[8],hn[9]);   wv[1]=pack2(hn[10],hn[11]); *(u32x2*)(hw + 256) = wv; }
            { u32x2 wv; wv[0]=pack2(hn[12],hn[13]); wv[1]=pack2(hn[14],hn[15]); *(u32x2*)(hw + 384) = wv; }

            // fc_out diff partial (quad qq covers m = ms*32 + 8*qq + 4*kg + 0..3)
            const f32x4 w0 = *(const f32x4*)&wdL[ms*32      + 4*kg];
            const f32x4 w1 = *(const f32x4*)&wdL[ms*32 + 8  + 4*kg];
            const f32x4 w2 = *(const f32x4*)&wdL[ms*32 + 16 + 4*kg];
            const f32x4 w3 = *(const f32x4*)&wdL[ms*32 + 24 + 4*kg];
            float pd = hn[0]*w0[0];
            pd = fmaf(hn[1],w0[1],pd);  pd = fmaf(hn[2],w0[2],pd);  pd = fmaf(hn[3],w0[3],pd);
            pd = fmaf(hn[4],w1[0],pd);  pd = fmaf(hn[5],w1[1],pd);  pd = fmaf(hn[6],w1[2],pd);  pd = fmaf(hn[7],w1[3],pd);
            pd = fmaf(hn[8],w2[0],pd);  pd = fmaf(hn[9],w2[1],pd);  pd = fmaf(hn[10],w2[2],pd); pd = fmaf(hn[11],w2[3],pd);
            pd = fmaf(hn[12],w3[0],pd); pd = fmaf(hn[13],w3[1],pd); pd = fmaf(hn[14],w3[2],pd); pd = fmaf(hn[15],w3[3],pd);
            pd += __shfl_xor(pd, 32);
            if (l < 32) diffP[nt*32 + n31][ms] = pd;
        }
        __syncthreads();

        // ============ Phase B: fc_in (all 8 waves, 1 job each) + out-store ============
        if (d < DAYS-1){
            const short8* hb = (const short8*)(hWr + ntF*4608);
            const short8* fp = (const short8*)finL + msF*576;
            f32x16 ax = {0,0,0,0,0,0,0,0,0,0,0,0,0,0,0,0};
            #pragma unroll
            for (int ks = 0; ks < 9; ++ks)            // ks=8: bias col x ones row
                ax = MFMA32(fp[ks*64 + l], hb[ks*64 + l], ax);
            u32* xw = (u32*)xL + ntF*1024 + msF*512 + n31*4 + 2*kg;
            { u32x2 wv; wv[0]=pack2(fmaxf(ax[0],0.f), fmaxf(ax[1],0.f));   wv[1]=pack2(fmaxf(ax[2],0.f), fmaxf(ax[3],0.f));   *(u32x2*)(xw      ) = wv; }
            { u32x2 wv; wv[0]=pack2(fmaxf(ax[4],0.f), fmaxf(ax[5],0.f));   wv[1]=pack2(fmaxf(ax[6],0.f), fmaxf(ax[7],0.f));   *(u32x2*)(xw + 128) = wv; }
            { u32x2 wv; wv[0]=pack2(fmaxf(ax[8],0.f), fmaxf(ax[9],0.f));   wv[1]=pack2(fmaxf(ax[10],0.f),fmaxf(ax[11],0.f));  *(u32x2*)(xw + 256) = wv; }
            { u32x2 wv; wv[0]=pack2(fmaxf(ax[12],0.f),fmaxf(ax[13],0.f));  wv[1]=pack2(fmaxf(ax[14],0.f),fmaxf(ax[15],0.f));  *(u32x2*)(xw + 384) = wv; }
        }
        if (wid < 4 && l < 32){
            const int row = wid*32 + l;
            const f32x4 v = *(const f32x4*)&diffP[row][0];
            const float s = (v[0] + v[1]) + (v[2] + v[3]);
            const float p0 = sig2(s + bd);
            f32x2 o = {p0, 1.0f - p0};
            *(f32x2*)(outp + ((size_t)(row0 + row)*DAYS + d)*NOUT) = o;
        }
        __syncthreads();
    }
}

extern "C" void kernel_launch(void* const* d_in, const int* in_sizes, int n_in,
                              void* d_out, int out_size, void* d_ws, size_t ws_size,
                              hipStream_t stream) {
    const float* hx       = (const float*)d_in[0];
    const float* w_ih     = (const float*)d_in[1];
    const float* w_hh     = (const float*)d_in[2];
    const float* b_ih     = (const float*)d_in[3];
    const float* b_hh     = (const float*)d_in[4];
    const float* fc_in_w  = (const float*)d_in[5];
    const float* fc_in_b  = (const float*)d_in[6];
    const float* fc_out_w = (const float*)d_in[7];
    const float* fc_out_b = (const float*)d_in[8];
    const float* span_w   = (const float*)d_in[9];
    const float* span_b   = (const float*)d_in[10];
    float* out = (float*)d_out;

    const int bs = in_sizes[0] / HID;            // 32768
    dim3 grid(bs / ROWS), block(NTH);
    gru32<<<grid, block, 0, stream>>>(hx, w_ih, w_hh, b_ih, b_hh,
                                      fc_in_w, fc_in_b, fc_out_w, fc_out_b,
                                      span_w, span_b, out, bs);
}

// Round 9
// 155.291 us; speedup vs baseline: 1.3136x; 1.3136x over previous
//
#include <hip/hip_runtime.h>
#include <hip/hip_bf16.h>

#define HID 128
#define INP 64
#define SPANN 8
#define NOUT 2
#define DAYS 20
#define RT 4                 // 16-row tiles per block
#define ROWS (16*RT)         // 64 batch rows per block
#define NTH 512              // 8 waves

typedef __attribute__((ext_vector_type(8))) short short8;
typedef __attribute__((ext_vector_type(4))) float f32x4;
typedef __attribute__((ext_vector_type(2))) float f32x2;
typedef unsigned int u32;
typedef __attribute__((ext_vector_type(2))) u32 u32x2;
typedef unsigned short u16;

#define MFMA(a,b,c) __builtin_amdgcn_mfma_f32_16x16x32_bf16(a,b,c,0,0,0)
#define RCPF(x)  __builtin_amdgcn_rcpf(x)
#define EXP2F(x) __builtin_amdgcn_exp2f(x)
#define LOG2E   1.4426950408889634f
#define NLOG2E  (-1.4426950408889634f)
#define LOG2E2  2.8853900817779268f

__device__ __forceinline__ u32 pack2(float a, float b){
    __hip_bfloat162 h = __float22bfloat162_rn(float2{a, b});
    u32 r; __builtin_memcpy(&r, &h, 4); return r;
}
// pre-scaled activation arg (already multiplied by -log2e)
__device__ __forceinline__ float sig2(float a){ return RCPF(1.0f + EXP2F(a)); }

union frag_u { short8 s; u32 w[4]; };
// load 8 consecutive f32, scale, convert to a bf16 MFMA fragment (4 VGPRs)
__device__ __forceinline__ short8 ldfrag(const float* p, float sc){
    const f32x4 a = *(const f32x4*)p;
    const f32x4 b = *(const f32x4*)(p+4);
    frag_u f;
    f.w[0] = pack2(sc*a[0],sc*a[1]); f.w[1] = pack2(sc*a[2],sc*a[3]);
    f.w[2] = pack2(sc*b[0],sc*b[1]); f.w[3] = pack2(sc*b[2],sc*b[3]);
    return f.s;
}

// Fragment conventions (16x16x32 bf16):
//  A: lane holds A[m = l&15][k = (l>>4)*8 + j]   (weights)
//  B: lane holds B[k = (l>>4)*8 + j][n = l&15]   (h^T / x^T, n = batch row)
//  D: lane holds D[m = (l>>4)*4 + q][n = l&15]   (m89-verified)
// h/x LDS tiles are fragment-major: k-step ks at ks*1024B + l*16B.
// R/Z (and fc_out-diff) weights+biases pre-scaled by -log2e, N by 2log2e.
// Gate update uses the FUSED 5-trans form:
//   eR=2^aR, rg=rcp(1+eR), eN=2^(rg*aNh+aNi), eZ=2^aZ
//   h' = (eN*eZ - eZ + h*(1+eN)) * rcp((1+eN)*(1+eZ))
// (limits: eZ->0 => h'=h; eZ->inf => h'=tanh; one rcp replaces two.)

// min-waves/EU=2 (NOT 4): R3/R8 showed tighter caps spill the resident
// weight fragments -> GB-scale scratch traffic. Actual VGPR must stay <=128.
__global__ __launch_bounds__(NTH, 2) void gru_mfma(
    const float* __restrict__ hx, const float* __restrict__ w_ih,
    const float* __restrict__ w_hh, const float* __restrict__ b_ih,
    const float* __restrict__ b_hh, const float* __restrict__ fc_in_w,
    const float* __restrict__ fc_in_b, const float* __restrict__ fc_out_w,
    const float* __restrict__ fc_out_b, const float* __restrict__ span_w,
    const float* __restrict__ span_b, float* __restrict__ out, int bs)
{
    __shared__ u16 hL[2][RT*2048];                       // 32 KiB, day-parity dbuf
    __shared__ u16 xL[RT*1024];                          // 8 KiB, single buffer
    __shared__ u16 finL[4*4*64*8];                       // 16 KiB fc_in_w A-frags
    __shared__ __attribute__((aligned(16))) float diffP[ROWS][12]; // b128-readable

    const int tid = threadIdx.x;
    const int wid = tid >> 6;        // 0..7, owns gate m-tiles {wid, wid+8, wid+16}
    const int l   = tid & 63;
    const int r15 = l & 15;
    const int hi  = l >> 4;
    const int row0 = blockIdx.x * ROWS;
    const int mB  = wid & 3;         // fc_in m-tile for Phase B
    const int rtB_off = wid >> 2;    // fc_in row-tile offset (0/1)

    // ---- resident weight fragments (gates only), pre-scaled ----
    short8 whhR[4], whhZ[4], whhN[4];
    short8 wihR[2], wihZ[2], wihN[2];
    const int g0 = wid*16 + r15;
    #pragma unroll
    for (int ks = 0; ks < 4; ++ks){
        whhR[ks] = ldfrag(w_hh + (size_t)(      g0)*HID + ks*32 + hi*8, NLOG2E);
        whhZ[ks] = ldfrag(w_hh + (size_t)(128 + g0)*HID + ks*32 + hi*8, NLOG2E);
        whhN[ks] = ldfrag(w_hh + (size_t)(256 + g0)*HID + ks*32 + hi*8, LOG2E2);
    }
    #pragma unroll
    for (int ks = 0; ks < 2; ++ks){
        wihR[ks] = ldfrag(w_ih + (size_t)(      g0)*INP + ks*32 + hi*8, NLOG2E);
        wihZ[ks] = ldfrag(w_ih + (size_t)(128 + g0)*INP + ks*32 + hi*8, NLOG2E);
        wihN[ks] = ldfrag(w_ih + (size_t)(256 + g0)*INP + ks*32 + hi*8, LOG2E2);
    }

    // ---- stage fc_in_w into LDS as A-fragments (one copy for all waves) ----
    for (int s = tid; s < 1024; s += NTH) {
        const int mt = s >> 8, ks = (s >> 6) & 3, ll = s & 63;
        short8 f = ldfrag(fc_in_w + (size_t)(mt*16 + (ll&15))*HID + ks*32 + (ll>>4)*8, 1.0f);
        *((short8*)finL + s) = f;
    }

    // ---- biases (pre-scaled) / fc_out diff weights (pre-scaled) ----
    f32x4 bRv, bZv, bNiv, bNhv, fbv, wd4;
    const int c0 = wid*16 + hi*4;
    #pragma unroll
    for (int q = 0; q < 4; ++q){
        const int g = c0 + q;
        bRv[q]  = NLOG2E*(b_ih[g]       + b_hh[g]);
        bZv[q]  = NLOG2E*(b_ih[128 + g] + b_hh[128 + g]);
        bNiv[q] = LOG2E2* b_ih[256 + g];
        bNhv[q] = LOG2E2* b_hh[256 + g];
        fbv[q]  = fc_in_b[mB*16 + hi*4 + q];
        wd4[q]  = NLOG2E*(fc_out_w[g] - fc_out_w[HID + g]);
    }
    const float bd = NLOG2E*(fc_out_b[0] - fc_out_b[1]);

    // scatter index (u32 units) of this thread's 4 output cols in a frag-major tile
    const int wu32  = (wid>>1)*256 + (((wid&1)*2 + (hi>>1))*16 + r15)*4 + (hi&1)*2;
    const int xwu32 = (mB >>1)*256 + (((mB &1)*2 + (hi>>1))*16 + r15)*4 + (hi&1)*2;

    // ---- h_old f32 regs + fill hL[0] + zero xL ----
    f32x4 hOld0, hOld1, hOld2, hOld3;
    {
        #define LOADH(RTG, HO) do { \
            const f32x4 h4 = *(const f32x4*)(hx + (size_t)(row0 + (RTG)*16 + r15)*HID + c0); \
            HO = h4; \
            u32x2 wv; wv[0] = pack2(h4[0], h4[1]); wv[1] = pack2(h4[2], h4[3]); \
            *(u32x2*)((u32*)&hL[0][(RTG)*2048] + wu32) = wv; } while(0)
        LOADH(0, hOld0); LOADH(1, hOld1); LOADH(2, hOld2); LOADH(3, hOld3);
        #undef LOADH
        u32* xb = (u32*)&xL[0];
        for (int i = tid; i < RT*512; i += NTH) xb[i] = 0u;
    }
    __syncthreads();

    // ---- span head: waves 0-3, one row-tile each (reads hL[0]) ----
    if (wid < 4){
        const short8 zz = {0,0,0,0,0,0,0,0};
        short8 spw[4];
        #pragma unroll
        for (int ks = 0; ks < 4; ++ks)
            spw[ks] = (r15 < SPANN) ? ldfrag(span_w + (size_t)r15*HID + ks*32 + hi*8, 1.0f) : zz;
        f32x4 acc = {0.f,0.f,0.f,0.f};
        #pragma unroll
        for (int q = 0; q < 4; ++q) if (hi < 2) acc[q] = span_b[hi*4 + q];
        const short8* hf = (const short8*)&hL[0][wid*2048];
        #pragma unroll
        for (int ks = 0; ks < 4; ++ks) acc = MFMA(spw[ks], hf[ks*64 + l], acc);
        if (hi < 2){
            float m = fmaxf(fmaxf(acc[0], acc[1]), fmaxf(acc[2], acc[3]));
            m = fmaxf(m, __shfl_xor(m, 16));
            float e0 = EXP2F(LOG2E*(acc[0]-m)), e1 = EXP2F(LOG2E*(acc[1]-m));
            float e2 = EXP2F(LOG2E*(acc[2]-m)), e3 = EXP2F(LOG2E*(acc[3]-m));
            float s = e0 + e1 + e2 + e3;
            s += __shfl_xor(s, 16);
            const float inv = RCPF(s);
            f32x4 o = {e0*inv, e1*inv, e2*inv, e3*inv};
            *(f32x4*)(out + (size_t)(row0 + wid*16 + r15)*SPANN + hi*4) = o;
        }
    }

    float* __restrict__ outp = out + (size_t)bs * SPANN;

    // ---- macros: one gate tile (A), one fc_in unit + out-store (B) ----
    #define TILE_A(RTG, hRd_, hWr_, HO) do { \
        const short8* hf = (const short8*)((hRd_) + (RTG)*2048); \
        const short8* xf = (const short8*)(xL + (RTG)*1024); \
        const short8 h0=hf[l], h1=hf[64+l], h2=hf[128+l], h3=hf[192+l]; \
        const short8 x0=xf[l], x1=xf[64+l]; \
        f32x4 aR  = MFMA(whhR[0], h0, bRv); \
        f32x4 aZ  = MFMA(whhZ[0], h0, bZv); \
        f32x4 aNh = MFMA(whhN[0], h0, bNhv); \
        aR = MFMA(whhR[1],h1,aR); aZ = MFMA(whhZ[1],h1,aZ); aNh = MFMA(whhN[1],h1,aNh); \
        aR = MFMA(whhR[2],h2,aR); aZ = MFMA(whhZ[2],h2,aZ); aNh = MFMA(whhN[2],h2,aNh); \
        aR = MFMA(whhR[3],h3,aR); aZ = MFMA(whhZ[3],h3,aZ); aNh = MFMA(whhN[3],h3,aNh); \
        f32x4 aNi = MFMA(wihN[0], x0, bNiv); \
        aR = MFMA(wihR[0],x0,aR); aZ = MFMA(wihZ[0],x0,aZ); \
        aNi = MFMA(wihN[1],x1,aNi); \
        aR = MFMA(wihR[1],x1,aR); aZ = MFMA(wihZ[1],x1,aZ); \
        float hn[4]; \
        _Pragma("unroll") for (int q=0;q<4;++q){ \
            const float eR = EXP2F(aR[q]); \
            const float rg = RCPF(1.0f + eR); \
            const float eN = EXP2F(fmaf(rg, aNh[q], aNi[q])); \
            const float eZ = EXP2F(aZ[q]); \
            const float t1 = eN * eZ; \
            const float num = fmaf(HO[q], eN, HO[q]) + (t1 - eZ); \
            const float den = (1.0f + eN) + (eZ + t1); \
            hn[q] = num * RCPF(den); \
            HO[q] = hn[q]; } \
        u32x2 wv; wv[0]=pack2(hn[0],hn[1]); wv[1]=pack2(hn[2],hn[3]); \
        *(u32x2*)((hWr_) + (RTG)*1024 + wu32) = wv; \
        float pd = hn[0]*wd4[0]; pd = fmaf(hn[1],wd4[1],pd); \
        pd = fmaf(hn[2],wd4[2],pd); pd = fmaf(hn[3],wd4[3],pd); \
        pd += __shfl_xor(pd, 16); pd += __shfl_xor(pd, 32); \
        if (hi == 0) diffP[(RTG)*16 + r15][wid] = pd; \
    } while(0)

    #define OUT_STORE(d_, gb_) do { \
        if (wid == 7 && l < 32) { \
            const int rowIdx = (gb_)*32 + l; \
            const f32x4 v0 = *(const f32x4*)&diffP[rowIdx][0]; \
            const f32x4 v1 = *(const f32x4*)&diffP[rowIdx][4]; \
            const float s = ((v0[0]+v0[1])+(v0[2]+v0[3])) + ((v1[0]+v1[1])+(v1[2]+v1[3])); \
            const float p0 = sig2(s + bd); \
            f32x2 o = {p0, 1.0f - p0}; \
            *(f32x2*)(outp + ((size_t)(row0 + rowIdx)*DAYS + (d_))*NOUT) = o; \
        } \
    } while(0)

    #define TILE_B(d_, gb_, hSrc) do { \
        if ((d_) < DAYS-1) { \
            const int rtB = 2*(gb_) + rtB_off; \
            const short8* hf = (const short8*)((hSrc) + rtB*2048); \
            const short8 h0=hf[l], h1=hf[64+l], h2=hf[128+l], h3=hf[192+l]; \
            const short8* fp = (const short8*)finL + mB*256 + l; \
            f32x4 ax = MFMA(fp[0],   h0, fbv); \
            ax       = MFMA(fp[64],  h1, ax); \
            ax       = MFMA(fp[128], h2, ax); \
            ax       = MFMA(fp[192], h3, ax); \
            u32x2 wv; \
            wv[0] = pack2(fmaxf(ax[0],0.f), fmaxf(ax[1],0.f)); \
            wv[1] = pack2(fmaxf(ax[2],0.f), fmaxf(ax[3],0.f)); \
            *(u32x2*)((u32*)xL + rtB*512 + xwu32) = wv; \
        } \
        OUT_STORE(d_, gb_); \
    } while(0)

    // ---- day loop: two super-phases, A(Gx) overlapped with B(Gy).
    // Race-safety: SP-even A reads xL{0,1}, B writes xL{2,3} (disjoint);
    // SP-odd A reads xL{2,3}, B writes xL{0,1} whose readers finished before
    // the preceding barrier. B's h reads are of tiles written before the
    // preceding barrier. OUT reads diffP rows written before it. ----
    #pragma unroll 1
    for (int d = 0; d < DAYS; ++d){
        const u16* hRd = hL[d & 1];
        u32*       hWr = (u32*)hL[(d & 1) ^ 1];

        // SP even: A(G0, d)  ||  B(G1, d-1) + out(G1, d-1)
        TILE_A(0, hRd, hWr, hOld0);
        TILE_A(1, hRd, hWr, hOld1);
        if (d > 0) TILE_B(d-1, 1, hRd);
        __syncthreads();

        // SP odd:  A(G1, d)  ||  B(G0, d) + out(G0, d)
        TILE_A(2, hRd, hWr, hOld2);
        TILE_A(3, hRd, hWr, hOld3);
        TILE_B(d, 0, (const u16*)hWr);
        __syncthreads();
    }
    // epilogue: out(G1, last day)
    OUT_STORE(DAYS-1, 1);

    #undef TILE_A
    #undef TILE_B
    #undef OUT_STORE
}

extern "C" void kernel_launch(void* const* d_in, const int* in_sizes, int n_in,
                              void* d_out, int out_size, void* d_ws, size_t ws_size,
                              hipStream_t stream) {
    const float* hx       = (const float*)d_in[0];
    const float* w_ih     = (const float*)d_in[1];
    const float* w_hh     = (const float*)d_in[2];
    const float* b_ih     = (const float*)d_in[3];
    const float* b_hh     = (const float*)d_in[4];
    const float* fc_in_w  = (const float*)d_in[5];
    const float* fc_in_b  = (const float*)d_in[6];
    const float* fc_out_w = (const float*)d_in[7];
    const float* fc_out_b = (const float*)d_in[8];
    const float* span_w   = (const float*)d_in[9];
    const float* span_b   = (const float*)d_in[10];
    float* out = (float*)d_out;

    const int bs = in_sizes[0] / HID;            // 32768
    dim3 grid(bs / ROWS), block(NTH);
    gru_mfma<<<grid, block, 0, stream>>>(hx, w_ih, w_hh, b_ih, b_hh,
                                         fc_in_w, fc_in_b, fc_out_w, fc_out_b,
                                         span_w, span_b, out, bs);
}

// Round 10
// 145.652 us; speedup vs baseline: 1.4005x; 1.0662x over previous
//
#include <hip/hip_runtime.h>
#include <hip/hip_bf16.h>

#define HID 128
#define INP 64
#define SPANN 8
#define NOUT 2
#define DAYS 20
#define RT 4                 // 16-row tiles per block
#define ROWS (16*RT)         // 64 batch rows per block
#define NTH 512              // 8 waves

typedef __attribute__((ext_vector_type(8))) short short8;
typedef __attribute__((ext_vector_type(4))) float f32x4;
typedef __attribute__((ext_vector_type(2))) float f32x2;
typedef unsigned int u32;
typedef __attribute__((ext_vector_type(2))) u32 u32x2;
typedef unsigned short u16;

#define MFMA(a,b,c) __builtin_amdgcn_mfma_f32_16x16x32_bf16(a,b,c,0,0,0)
#define RCPF(x)  __builtin_amdgcn_rcpf(x)
#define EXP2F(x) __builtin_amdgcn_exp2f(x)
#define LOG2E   1.4426950408889634f
#define NLOG2E  (-1.4426950408889634f)
#define LOG2E2  2.8853900817779268f

__device__ __forceinline__ u32 pack2(float a, float b){
    __hip_bfloat162 h = __float22bfloat162_rn(float2{a, b});
    u32 r; __builtin_memcpy(&r, &h, 4); return r;
}
__device__ __forceinline__ float asF(u32 u){ union{u32 u; float f;} v; v.u = u; return v.f; }
// pre-scaled activations: arg already multiplied by -log2e (sig) / 2log2e (tanh)
__device__ __forceinline__ float sig2(float a){ return RCPF(1.0f + EXP2F(a)); }
__device__ __forceinline__ float tanh2(float a){ return fmaf(-2.0f, RCPF(1.0f + EXP2F(a)), 1.0f); }

union frag_u { short8 s; u32 w[4]; };
// load 8 consecutive f32, scale, convert to a bf16 MFMA fragment (4 VGPRs)
__device__ __forceinline__ short8 ldfrag(const float* p, float sc){
    const f32x4 a = *(const f32x4*)p;
    const f32x4 b = *(const f32x4*)(p+4);
    frag_u f;
    f.w[0] = pack2(sc*a[0],sc*a[1]); f.w[1] = pack2(sc*a[2],sc*a[3]);
    f.w[2] = pack2(sc*b[0],sc*b[1]); f.w[3] = pack2(sc*b[2],sc*b[3]);
    return f.s;
}

// Fragment conventions (16x16x32 bf16):
//  A: lane holds A[m = l&15][k = (l>>4)*8 + j]   (weights)
//  B: lane holds B[k = (l>>4)*8 + j][n = l&15]   (h^T / x^T, n = batch row)
//  D: lane holds D[m = (l>>4)*4 + q][n = l&15]   (m89-verified)
// h/x LDS tiles are fragment-major: k-step ks at ks*1024B + l*16B.
// R/Z (and fc_out-diff) weights+biases pre-scaled by -log2e, N by 2log2e.
// Gate trans form: separate sig2/tanh2 (R9's fused 5-trans form REGRESSED
// ~11us despite fewer trans ops — do not re-fuse).

// min-waves/EU=2 (NOT 4): R3/R8 showed tighter caps spill the resident
// weight fragments -> GB-scale scratch traffic. Actual VGPR must stay <=128
// (2048-reg pool / 128 = 16 waves/CU = two 8-wave blocks).
__global__ __launch_bounds__(NTH, 2) void gru_mfma(
    const float* __restrict__ hx, const float* __restrict__ w_ih,
    const float* __restrict__ w_hh, const float* __restrict__ b_ih,
    const float* __restrict__ b_hh, const float* __restrict__ fc_in_w,
    const float* __restrict__ fc_in_b, const float* __restrict__ fc_out_w,
    const float* __restrict__ fc_out_b, const float* __restrict__ span_w,
    const float* __restrict__ span_b, float* __restrict__ out, int bs)
{
    __shared__ u16 hL[2][RT*2048];                       // 32 KiB, day-parity dbuf
    __shared__ u16 xL[RT*1024];                          // 8 KiB, single buffer
    __shared__ float diffP[ROWS][9];                     // fc_out partials, stride 9 (conflict-free)

    const int tid = threadIdx.x;
    const int wid = tid >> 6;        // 0..7, owns gate m-tiles {wid, wid+8, wid+16}
    const int l   = tid & 63;
    const int r15 = l & 15;
    const int hi  = l >> 4;
    const int row0 = blockIdx.x * ROWS;
    const int mB  = wid & 3;         // fc_in m-tile for Phase B
    const int rtB_off = wid >> 2;    // fc_in row-tile offset (0/1)

    // ---- resident weight fragments, pre-scaled ----
    short8 whhR[4], whhZ[4], whhN[4];
    short8 wihR[2], wihZ[2], wihN[2];
    short8 fwA[4];                   // fc_in m-tile mB (resident: saves 4 LDS b128/wave/day)
    const int g0 = wid*16 + r15;
    #pragma unroll
    for (int ks = 0; ks < 4; ++ks){
        whhR[ks] = ldfrag(w_hh + (size_t)(      g0)*HID + ks*32 + hi*8, NLOG2E);
        whhZ[ks] = ldfrag(w_hh + (size_t)(128 + g0)*HID + ks*32 + hi*8, NLOG2E);
        whhN[ks] = ldfrag(w_hh + (size_t)(256 + g0)*HID + ks*32 + hi*8, LOG2E2);
        fwA[ks]  = ldfrag(fc_in_w + (size_t)(mB*16 + r15)*HID + ks*32 + hi*8, 1.0f);
    }
    #pragma unroll
    for (int ks = 0; ks < 2; ++ks){
        wihR[ks] = ldfrag(w_ih + (size_t)(      g0)*INP + ks*32 + hi*8, NLOG2E);
        wihZ[ks] = ldfrag(w_ih + (size_t)(128 + g0)*INP + ks*32 + hi*8, NLOG2E);
        wihN[ks] = ldfrag(w_ih + (size_t)(256 + g0)*INP + ks*32 + hi*8, LOG2E2);
    }

    // ---- biases (pre-scaled) / fc_out diff weights (pre-scaled) ----
    f32x4 bRv, bZv, bNiv, bNhv, fbv, wd4;
    const int c0 = wid*16 + hi*4;
    #pragma unroll
    for (int q = 0; q < 4; ++q){
        const int g = c0 + q;
        bRv[q]  = NLOG2E*(b_ih[g]       + b_hh[g]);
        bZv[q]  = NLOG2E*(b_ih[128 + g] + b_hh[128 + g]);
        bNiv[q] = LOG2E2* b_ih[256 + g];
        bNhv[q] = LOG2E2* b_hh[256 + g];
        fbv[q]  = fc_in_b[mB*16 + hi*4 + q];
        wd4[q]  = NLOG2E*(fc_out_w[g] - fc_out_w[HID + g]);
    }
    const float bd = NLOG2E*(fc_out_b[0] - fc_out_b[1]);

    // scatter index (u32 units) of this thread's 4 output cols in a frag-major tile
    const int wu32  = (wid>>1)*256 + (((wid&1)*2 + (hi>>1))*16 + r15)*4 + (hi&1)*2;
    const int xwu32 = (mB >>1)*256 + (((mB &1)*2 + (hi>>1))*16 + r15)*4 + (hi&1)*2;

    // ---- fill hL[0] from hx + zero xL (h state lives ONLY in LDS as bf16) ----
    {
        #pragma unroll
        for (int rt = 0; rt < RT; ++rt){
            const f32x4 h4 = *(const f32x4*)(hx + (size_t)(row0 + rt*16 + r15)*HID + c0);
            u32x2 wv; wv[0] = pack2(h4[0], h4[1]); wv[1] = pack2(h4[2], h4[3]);
            *(u32x2*)((u32*)&hL[0][rt*2048] + wu32) = wv;
        }
        u32* xb = (u32*)&xL[0];
        for (int i = tid; i < RT*512; i += NTH) xb[i] = 0u;
    }
    __syncthreads();

    // ---- span head: waves 0-3, one row-tile each (reads hL[0]) ----
    if (wid < 4){
        const short8 zz = {0,0,0,0,0,0,0,0};
        short8 spw[4];
        #pragma unroll
        for (int ks = 0; ks < 4; ++ks)
            spw[ks] = (r15 < SPANN) ? ldfrag(span_w + (size_t)r15*HID + ks*32 + hi*8, 1.0f) : zz;
        f32x4 acc = {0.f,0.f,0.f,0.f};
        #pragma unroll
        for (int q = 0; q < 4; ++q) if (hi < 2) acc[q] = span_b[hi*4 + q];
        const short8* hf = (const short8*)&hL[0][wid*2048];
        #pragma unroll
        for (int ks = 0; ks < 4; ++ks) acc = MFMA(spw[ks], hf[ks*64 + l], acc);
        if (hi < 2){
            float m = fmaxf(fmaxf(acc[0], acc[1]), fmaxf(acc[2], acc[3]));
            m = fmaxf(m, __shfl_xor(m, 16));
            float e0 = EXP2F(LOG2E*(acc[0]-m)), e1 = EXP2F(LOG2E*(acc[1]-m));
            float e2 = EXP2F(LOG2E*(acc[2]-m)), e3 = EXP2F(LOG2E*(acc[3]-m));
            float s = e0 + e1 + e2 + e3;
            s += __shfl_xor(s, 16);
            const float inv = RCPF(s);
            f32x4 o = {e0*inv, e1*inv, e2*inv, e3*inv};
            *(f32x4*)(out + (size_t)(row0 + wid*16 + r15)*SPANN + hi*4) = o;
        }
    }

    float* __restrict__ outp = out + (size_t)bs * SPANN;

    // ---- macros: one gate tile (A), one fc_in unit + out-store (B) ----
    #define TILE_A(RTG, hRd_, hWr_) do { \
        const short8* hf = (const short8*)((hRd_) + (RTG)*2048); \
        const short8* xf = (const short8*)(xL + (RTG)*1024); \
        const short8 h0=hf[l], h1=hf[64+l], h2=hf[128+l], h3=hf[192+l]; \
        const short8 x0=xf[l], x1=xf[64+l]; \
        const u32x2 ho = *(const u32x2*)((const u32*)(hRd_) + (RTG)*1024 + wu32); \
        f32x4 aR  = MFMA(whhR[0], h0, bRv); \
        f32x4 aZ  = MFMA(whhZ[0], h0, bZv); \
        f32x4 aNh = MFMA(whhN[0], h0, bNhv); \
        aR = MFMA(whhR[1],h1,aR); aZ = MFMA(whhZ[1],h1,aZ); aNh = MFMA(whhN[1],h1,aNh); \
        aR = MFMA(whhR[2],h2,aR); aZ = MFMA(whhZ[2],h2,aZ); aNh = MFMA(whhN[2],h2,aNh); \
        aR = MFMA(whhR[3],h3,aR); aZ = MFMA(whhZ[3],h3,aZ); aNh = MFMA(whhN[3],h3,aNh); \
        f32x4 aNi = MFMA(wihN[0], x0, bNiv); \
        aR = MFMA(wihR[0],x0,aR); aZ = MFMA(wihZ[0],x0,aZ); \
        aNi = MFMA(wihN[1],x1,aNi); \
        aR = MFMA(wihR[1],x1,aR); aZ = MFMA(wihZ[1],x1,aZ); \
        const float hold[4] = { asF(ho[0]<<16), asF(ho[0]&0xFFFF0000u), \
                                asF(ho[1]<<16), asF(ho[1]&0xFFFF0000u) }; \
        float hn[4]; \
        _Pragma("unroll") for (int q=0;q<4;++q){ \
            const float rg = sig2(aR[q]); const float zg = sig2(aZ[q]); \
            const float nn = tanh2(fmaf(rg, aNh[q], aNi[q])); \
            hn[q] = fmaf(zg, hold[q]-nn, nn); } \
        u32x2 wv; wv[0]=pack2(hn[0],hn[1]); wv[1]=pack2(hn[2],hn[3]); \
        *(u32x2*)((hWr_) + (RTG)*1024 + wu32) = wv; \
        float pd = hn[0]*wd4[0]; pd = fmaf(hn[1],wd4[1],pd); \
        pd = fmaf(hn[2],wd4[2],pd); pd = fmaf(hn[3],wd4[3],pd); \
        pd += __shfl_xor(pd, 16); pd += __shfl_xor(pd, 32); \
        if (hi == 0) diffP[(RTG)*16 + r15][wid] = pd; \
    } while(0)

    #define OUT_STORE(d_, gb_) do { \
        if (wid == 7 && l < 32) { \
            const int rowIdx = (gb_)*32 + l; \
            const float* dp = &diffP[rowIdx][0]; \
            const float s = ((dp[0]+dp[1])+(dp[2]+dp[3])) + ((dp[4]+dp[5])+(dp[6]+dp[7])); \
            const float p0 = sig2(s + bd); \
            f32x2 o = {p0, 1.0f - p0}; \
            *(f32x2*)(outp + ((size_t)(row0 + rowIdx)*DAYS + (d_))*NOUT) = o; \
        } \
    } while(0)

    #define TILE_B(d_, gb_, hSrc) do { \
        if ((d_) < DAYS-1) { \
            const int rtB = 2*(gb_) + rtB_off; \
            const short8* hf = (const short8*)((hSrc) + rtB*2048); \
            const short8 h0=hf[l], h1=hf[64+l], h2=hf[128+l], h3=hf[192+l]; \
            f32x4 ax = MFMA(fwA[0], h0, fbv); \
            ax       = MFMA(fwA[1], h1, ax); \
            ax       = MFMA(fwA[2], h2, ax); \
            ax       = MFMA(fwA[3], h3, ax); \
            u32x2 wv; \
            wv[0] = pack2(fmaxf(ax[0],0.f), fmaxf(ax[1],0.f)); \
            wv[1] = pack2(fmaxf(ax[2],0.f), fmaxf(ax[3],0.f)); \
            *(u32x2*)((u32*)xL + rtB*512 + xwu32) = wv; \
        } \
        OUT_STORE(d_, gb_); \
    } while(0)

    // ---- day loop: two super-phases, A(Gx) overlapped with B(Gy).
    // Race-safety: SP-even A reads xL{0,1}, B writes xL{2,3} (disjoint);
    // SP-odd A reads xL{2,3}, B writes xL{0,1} whose readers finished before
    // the preceding barrier. B's h reads are of tiles written before the
    // preceding barrier. OUT reads diffP rows written before it. ----
    #pragma unroll 1
    for (int d = 0; d < DAYS; ++d){
        const u16* hRd = hL[d & 1];
        u32*       hWr = (u32*)hL[(d & 1) ^ 1];

        // SP even: A(G0, d)  ||  B(G1, d-1) + out(G1, d-1)
        TILE_A(0, hRd, hWr);
        TILE_A(1, hRd, hWr);
        if (d > 0) TILE_B(d-1, 1, hRd);
        __syncthreads();

        // SP odd:  A(G1, d)  ||  B(G0, d) + out(G0, d)
        TILE_A(2, hRd, hWr);
        TILE_A(3, hRd, hWr);
        TILE_B(d, 0, (const u16*)hWr);
        __syncthreads();
    }
    // epilogue: out(G1, last day)
    OUT_STORE(DAYS-1, 1);

    #undef TILE_A
    #undef TILE_B
    #undef OUT_STORE
}

extern "C" void kernel_launch(void* const* d_in, const int* in_sizes, int n_in,
                              void* d_out, int out_size, void* d_ws, size_t ws_size,
                              hipStream_t stream) {
    const float* hx       = (const float*)d_in[0];
    const float* w_ih     = (const float*)d_in[1];
    const float* w_hh     = (const float*)d_in[2];
    const float* b_ih     = (const float*)d_in[3];
    const float* b_hh     = (const float*)d_in[4];
    const float* fc_in_w  = (const float*)d_in[5];
    const float* fc_in_b  = (const float*)d_in[6];
    const float* fc_out_w = (const float*)d_in[7];
    const float* fc_out_b = (const float*)d_in[8];
    const float* span_w   = (const float*)d_in[9];
    const float* span_b   = (const float*)d_in[10];
    float* out = (float*)d_out;

    const int bs = in_sizes[0] / HID;            // 32768
    dim3 grid(bs / ROWS), block(NTH);
    gru_mfma<<<grid, block, 0, stream>>>(hx, w_ih, w_hh, b_ih, b_hh,
                                         fc_in_w, fc_in_b, fc_out_w, fc_out_b,
                                         span_w, span_b, out, bs);
}

// Round 11
// 142.938 us; speedup vs baseline: 1.4271x; 1.0190x over previous
//
#include <hip/hip_runtime.h>
#include <hip/hip_bf16.h>

#define HID 128
#define INP 64
#define SPANN 8
#define NOUT 2
#define DAYS 20
#define RT 4                 // 16-row tiles per block
#define ROWS (16*RT)         // 64 batch rows per block
#define NTH 512              // 8 waves

typedef __attribute__((ext_vector_type(8))) short short8;
typedef __attribute__((ext_vector_type(4))) float f32x4;
typedef __attribute__((ext_vector_type(2))) float f32x2;
typedef unsigned int u32;
typedef __attribute__((ext_vector_type(2))) u32 u32x2;
typedef unsigned short u16;

#define MFMA(a,b,c) __builtin_amdgcn_mfma_f32_16x16x32_bf16(a,b,c,0,0,0)
#define RCPF(x)  __builtin_amdgcn_rcpf(x)
#define EXP2F(x) __builtin_amdgcn_exp2f(x)
#define LOG2E   1.4426950408889634f
#define NLOG2E  (-1.4426950408889634f)
#define LOG2E2  2.8853900817779268f

__device__ __forceinline__ u32 pack2(float a, float b){
    __hip_bfloat162 h = __float22bfloat162_rn(float2{a, b});
    u32 r; __builtin_memcpy(&r, &h, 4); return r;
}
__device__ __forceinline__ float asF(u32 u){ union{u32 u; float f;} v; v.u = u; return v.f; }
// pre-scaled activations: arg already multiplied by -log2e (sig) / 2log2e (tanh)
__device__ __forceinline__ float sig2(float a){ return RCPF(1.0f + EXP2F(a)); }
__device__ __forceinline__ float tanh2(float a){ return fmaf(-2.0f, RCPF(1.0f + EXP2F(a)), 1.0f); }

union frag_u { short8 s; u32 w[4]; };
// load 8 consecutive f32, scale, convert to a bf16 MFMA fragment (4 VGPRs)
__device__ __forceinline__ short8 ldfrag(const float* p, float sc){
    const f32x4 a = *(const f32x4*)p;
    const f32x4 b = *(const f32x4*)(p+4);
    frag_u f;
    f.w[0] = pack2(sc*a[0],sc*a[1]); f.w[1] = pack2(sc*a[2],sc*a[3]);
    f.w[2] = pack2(sc*b[0],sc*b[1]); f.w[3] = pack2(sc*b[2],sc*b[3]);
    return f.s;
}

// Fragment conventions (16x16x32 bf16):
//  A: lane holds A[m = l&15][k = (l>>4)*8 + j]   (weights)
//  B: lane holds B[k = (l>>4)*8 + j][n = l&15]   (h^T / x^T, n = batch row)
//  D: lane holds D[m = (l>>4)*4 + q][n = l&15]   (m89-verified)
// h/x LDS tiles are fragment-major: k-step ks at ks*1024B + l*16B.
// R/Z (and fc_out-diff) weights+biases pre-scaled by -log2e, N by 2log2e.
//
// CHAMPION CONFIG (R6 = 143.7us). A/B ledger of failed alternatives:
//  - R7 wave-stagger + s_setprio: 155.6 (barrier-locked setprio is null/neg)
//  - R8 32x32x16 tile: 204 (needs ~270 VGPR -> spill at 128 cap)
//  - R9 fused 5-trans gate form: 155.3 (longer serial chain beats op count)
//  - R10 fc_in weights resident in VGPR: 145.7 (neutral; VGPR 112->128)
// Pipe budget at 164us dispatch: MFMA ~43us (=dense-peak arithmetic floor),
// VALU+trans ~70us, LDS ~53us; sum ~= wall (barrier-lockstep serialization).

// min-waves/EU=2 (NOT 4): R3/R8 showed tighter caps spill the resident
// weight fragments -> GB-scale scratch traffic.
__global__ __launch_bounds__(NTH, 2) void gru_mfma(
    const float* __restrict__ hx, const float* __restrict__ w_ih,
    const float* __restrict__ w_hh, const float* __restrict__ b_ih,
    const float* __restrict__ b_hh, const float* __restrict__ fc_in_w,
    const float* __restrict__ fc_in_b, const float* __restrict__ fc_out_w,
    const float* __restrict__ fc_out_b, const float* __restrict__ span_w,
    const float* __restrict__ span_b, float* __restrict__ out, int bs)
{
    __shared__ u16 hL[2][RT*2048];                       // 32 KiB, day-parity dbuf
    __shared__ u16 xL[RT*1024];                          // 8 KiB, single buffer
    __shared__ u16 finL[4*4*64*8];                       // 16 KiB fc_in_w A-frags
    __shared__ float diffP[ROWS][9];                     // fc_out partials, stride 9

    const int tid = threadIdx.x;
    const int wid = tid >> 6;        // 0..7, owns gate m-tiles {wid, wid+8, wid+16}
    const int l   = tid & 63;
    const int r15 = l & 15;
    const int hi  = l >> 4;
    const int row0 = blockIdx.x * ROWS;
    const int mB  = wid & 3;         // fc_in m-tile for Phase B
    const int rtB_off = wid >> 2;    // fc_in row-tile offset (0/1)

    // ---- resident weight fragments (gates only), pre-scaled ----
    short8 whhR[4], whhZ[4], whhN[4];
    short8 wihR[2], wihZ[2], wihN[2];
    const int g0 = wid*16 + r15;
    #pragma unroll
    for (int ks = 0; ks < 4; ++ks){
        whhR[ks] = ldfrag(w_hh + (size_t)(      g0)*HID + ks*32 + hi*8, NLOG2E);
        whhZ[ks] = ldfrag(w_hh + (size_t)(128 + g0)*HID + ks*32 + hi*8, NLOG2E);
        whhN[ks] = ldfrag(w_hh + (size_t)(256 + g0)*HID + ks*32 + hi*8, LOG2E2);
    }
    #pragma unroll
    for (int ks = 0; ks < 2; ++ks){
        wihR[ks] = ldfrag(w_ih + (size_t)(      g0)*INP + ks*32 + hi*8, NLOG2E);
        wihZ[ks] = ldfrag(w_ih + (size_t)(128 + g0)*INP + ks*32 + hi*8, NLOG2E);
        wihN[ks] = ldfrag(w_ih + (size_t)(256 + g0)*INP + ks*32 + hi*8, LOG2E2);
    }

    // ---- stage fc_in_w into LDS as A-fragments (one copy for all waves) ----
    for (int s = tid; s < 1024; s += NTH) {
        const int mt = s >> 8, ks = (s >> 6) & 3, ll = s & 63;
        short8 f = ldfrag(fc_in_w + (size_t)(mt*16 + (ll&15))*HID + ks*32 + (ll>>4)*8, 1.0f);
        *((short8*)finL + s) = f;
    }

    // ---- biases (pre-scaled) / fc_out diff weights (pre-scaled) ----
    f32x4 bRv, bZv, bNiv, bNhv, fbv, wd4;
    const int c0 = wid*16 + hi*4;
    #pragma unroll
    for (int q = 0; q < 4; ++q){
        const int g = c0 + q;
        bRv[q]  = NLOG2E*(b_ih[g]       + b_hh[g]);
        bZv[q]  = NLOG2E*(b_ih[128 + g] + b_hh[128 + g]);
        bNiv[q] = LOG2E2* b_ih[256 + g];
        bNhv[q] = LOG2E2* b_hh[256 + g];
        fbv[q]  = fc_in_b[mB*16 + hi*4 + q];
        wd4[q]  = NLOG2E*(fc_out_w[g] - fc_out_w[HID + g]);
    }
    const float bd = NLOG2E*(fc_out_b[0] - fc_out_b[1]);

    // scatter index (u32 units) of this thread's 4 output cols in a frag-major tile
    const int wu32  = (wid>>1)*256 + (((wid&1)*2 + (hi>>1))*16 + r15)*4 + (hi&1)*2;
    const int xwu32 = (mB >>1)*256 + (((mB &1)*2 + (hi>>1))*16 + r15)*4 + (hi&1)*2;

    // ---- fill hL[0] from hx + zero xL (h state lives ONLY in LDS as bf16) ----
    {
        #pragma unroll
        for (int rt = 0; rt < RT; ++rt){
            const f32x4 h4 = *(const f32x4*)(hx + (size_t)(row0 + rt*16 + r15)*HID + c0);
            u32x2 wv; wv[0] = pack2(h4[0], h4[1]); wv[1] = pack2(h4[2], h4[3]);
            *(u32x2*)((u32*)&hL[0][rt*2048] + wu32) = wv;
        }
        u32* xb = (u32*)&xL[0];
        for (int i = tid; i < RT*512; i += NTH) xb[i] = 0u;
    }
    __syncthreads();

    // ---- span head: waves 0-3, one row-tile each (reads hL[0]) ----
    if (wid < 4){
        const short8 zz = {0,0,0,0,0,0,0,0};
        short8 spw[4];
        #pragma unroll
        for (int ks = 0; ks < 4; ++ks)
            spw[ks] = (r15 < SPANN) ? ldfrag(span_w + (size_t)r15*HID + ks*32 + hi*8, 1.0f) : zz;
        f32x4 acc = {0.f,0.f,0.f,0.f};
        #pragma unroll
        for (int q = 0; q < 4; ++q) if (hi < 2) acc[q] = span_b[hi*4 + q];
        const short8* hf = (const short8*)&hL[0][wid*2048];
        #pragma unroll
        for (int ks = 0; ks < 4; ++ks) acc = MFMA(spw[ks], hf[ks*64 + l], acc);
        if (hi < 2){
            float m = fmaxf(fmaxf(acc[0], acc[1]), fmaxf(acc[2], acc[3]));
            m = fmaxf(m, __shfl_xor(m, 16));
            float e0 = EXP2F(LOG2E*(acc[0]-m)), e1 = EXP2F(LOG2E*(acc[1]-m));
            float e2 = EXP2F(LOG2E*(acc[2]-m)), e3 = EXP2F(LOG2E*(acc[3]-m));
            float s = e0 + e1 + e2 + e3;
            s += __shfl_xor(s, 16);
            const float inv = RCPF(s);
            f32x4 o = {e0*inv, e1*inv, e2*inv, e3*inv};
            *(f32x4*)(out + (size_t)(row0 + wid*16 + r15)*SPANN + hi*4) = o;
        }
    }

    float* __restrict__ outp = out + (size_t)bs * SPANN;

    // ---- macros: one gate tile (A), one fc_in unit + out-store (B) ----
    #define TILE_A(RTG, hRd_, hWr_) do { \
        const short8* hf = (const short8*)((hRd_) + (RTG)*2048); \
        const short8* xf = (const short8*)(xL + (RTG)*1024); \
        const short8 h0=hf[l], h1=hf[64+l], h2=hf[128+l], h3=hf[192+l]; \
        const short8 x0=xf[l], x1=xf[64+l]; \
        const u32x2 ho = *(const u32x2*)((const u32*)(hRd_) + (RTG)*1024 + wu32); \
        f32x4 aR  = MFMA(whhR[0], h0, bRv); \
        f32x4 aZ  = MFMA(whhZ[0], h0, bZv); \
        f32x4 aNh = MFMA(whhN[0], h0, bNhv); \
        aR = MFMA(whhR[1],h1,aR); aZ = MFMA(whhZ[1],h1,aZ); aNh = MFMA(whhN[1],h1,aNh); \
        aR = MFMA(whhR[2],h2,aR); aZ = MFMA(whhZ[2],h2,aZ); aNh = MFMA(whhN[2],h2,aNh); \
        aR = MFMA(whhR[3],h3,aR); aZ = MFMA(whhZ[3],h3,aZ); aNh = MFMA(whhN[3],h3,aNh); \
        f32x4 aNi = MFMA(wihN[0], x0, bNiv); \
        aR = MFMA(wihR[0],x0,aR); aZ = MFMA(wihZ[0],x0,aZ); \
        aNi = MFMA(wihN[1],x1,aNi); \
        aR = MFMA(wihR[1],x1,aR); aZ = MFMA(wihZ[1],x1,aZ); \
        const float hold[4] = { asF(ho[0]<<16), asF(ho[0]&0xFFFF0000u), \
                                asF(ho[1]<<16), asF(ho[1]&0xFFFF0000u) }; \
        float hn[4]; \
        _Pragma("unroll") for (int q=0;q<4;++q){ \
            const float rg = sig2(aR[q]); const float zg = sig2(aZ[q]); \
            const float nn = tanh2(fmaf(rg, aNh[q], aNi[q])); \
            hn[q] = fmaf(zg, hold[q]-nn, nn); } \
        u32x2 wv; wv[0]=pack2(hn[0],hn[1]); wv[1]=pack2(hn[2],hn[3]); \
        *(u32x2*)((hWr_) + (RTG)*1024 + wu32) = wv; \
        float pd = hn[0]*wd4[0]; pd = fmaf(hn[1],wd4[1],pd); \
        pd = fmaf(hn[2],wd4[2],pd); pd = fmaf(hn[3],wd4[3],pd); \
        pd += __shfl_xor(pd, 16); pd += __shfl_xor(pd, 32); \
        if (hi == 0) diffP[(RTG)*16 + r15][wid] = pd; \
    } while(0)

    #define OUT_STORE(d_, gb_) do { \
        if (wid == 7 && l < 32) { \
            const int rowIdx = (gb_)*32 + l; \
            const float* dp = &diffP[rowIdx][0]; \
            const float s = ((dp[0]+dp[1])+(dp[2]+dp[3])) + ((dp[4]+dp[5])+(dp[6]+dp[7])); \
            const float p0 = sig2(s + bd); \
            f32x2 o = {p0, 1.0f - p0}; \
            *(f32x2*)(outp + ((size_t)(row0 + rowIdx)*DAYS + (d_))*NOUT) = o; \
        } \
    } while(0)

    #define TILE_B(d_, gb_, hSrc) do { \
        if ((d_) < DAYS-1) { \
            const int rtB = 2*(gb_) + rtB_off; \
            const short8* hf = (const short8*)((hSrc) + rtB*2048); \
            const short8 h0=hf[l], h1=hf[64+l], h2=hf[128+l], h3=hf[192+l]; \
            const short8* fp = (const short8*)finL + mB*256 + l; \
            f32x4 ax = MFMA(fp[0],   h0, fbv); \
            ax       = MFMA(fp[64],  h1, ax); \
            ax       = MFMA(fp[128], h2, ax); \
            ax       = MFMA(fp[192], h3, ax); \
            u32x2 wv; \
            wv[0] = pack2(fmaxf(ax[0],0.f), fmaxf(ax[1],0.f)); \
            wv[1] = pack2(fmaxf(ax[2],0.f), fmaxf(ax[3],0.f)); \
            *(u32x2*)((u32*)xL + rtB*512 + xwu32) = wv; \
        } \
        OUT_STORE(d_, gb_); \
    } while(0)

    // ---- day loop: two super-phases, A(Gx) overlapped with B(Gy).
    // Race-safety: SP-even A reads xL{0,1}, B writes xL{2,3} (disjoint);
    // SP-odd A reads xL{2,3}, B writes xL{0,1} whose readers finished before
    // the preceding barrier. B's h reads are of tiles written before the
    // preceding barrier. OUT reads diffP rows written before it. ----
    #pragma unroll 1
    for (int d = 0; d < DAYS; ++d){
        const u16* hRd = hL[d & 1];
        u32*       hWr = (u32*)hL[(d & 1) ^ 1];

        // SP even: A(G0, d)  ||  B(G1, d-1) + out(G1, d-1)
        TILE_A(0, hRd, hWr);
        TILE_A(1, hRd, hWr);
        if (d > 0) TILE_B(d-1, 1, hRd);
        __syncthreads();

        // SP odd:  A(G1, d)  ||  B(G0, d) + out(G0, d)
        TILE_A(2, hRd, hWr);
        TILE_A(3, hRd, hWr);
        TILE_B(d, 0, (const u16*)hWr);
        __syncthreads();
    }
    // epilogue: out(G1, last day)
    OUT_STORE(DAYS-1, 1);

    #undef TILE_A
    #undef TILE_B
    #undef OUT_STORE
}

extern "C" void kernel_launch(void* const* d_in, const int* in_sizes, int n_in,
                              void* d_out, int out_size, void* d_ws, size_t ws_size,
                              hipStream_t stream) {
    const float* hx       = (const float*)d_in[0];
    const float* w_ih     = (const float*)d_in[1];
    const float* w_hh     = (const float*)d_in[2];
    const float* b_ih     = (const float*)d_in[3];
    const float* b_hh     = (const float*)d_in[4];
    const float* fc_in_w  = (const float*)d_in[5];
    const float* fc_in_b  = (const float*)d_in[6];
    const float* fc_out_w = (const float*)d_in[7];
    const float* fc_out_b = (const float*)d_in[8];
    const float* span_w   = (const float*)d_in[9];
    const float* span_b   = (const float*)d_in[10];
    float* out = (float*)d_out;

    const int bs = in_sizes[0] / HID;            // 32768
    dim3 grid(bs / ROWS), block(NTH);
    gru_mfma<<<grid, block, 0, stream>>>(hx, w_ih, w_hh, b_ih, b_hh,
                                         fc_in_w, fc_in_b, fc_out_w, fc_out_b,
                                         span_w, span_b, out, bs);
}